// Round 2
// baseline (2204.727 us; speedup 1.0000x reference)
//
#include <hip/hip_runtime.h>

// ---------------------------------------------------------------------------
// LSTMGRUHybrid: B=512, T=512, D=128, H=128 (4H=512), G=128 (3G=384), F=160, C=64
// Round 2: scans restructured — gate math fully in MFMA C-layout registers,
// one barrier/step (double-buffered h), LN unfused into a separate pass.
// ---------------------------------------------------------------------------

typedef __attribute__((ext_vector_type(8))) short bf16x8;
typedef __attribute__((ext_vector_type(4))) float f32x4;
typedef __attribute__((ext_vector_type(4))) int i32x4;
typedef unsigned short u16;
typedef unsigned int u32;

#define BT 262144          // B*T
#define TT 512

__device__ __forceinline__ u16 f2bf(float f) {
  u32 u = __builtin_bit_cast(u32, f);
  u += 0x7fffu + ((u >> 16) & 1u);
  return (u16)(u >> 16);
}
__device__ __forceinline__ float bf2f(u16 h) {
  return __builtin_bit_cast(float, (u32)h << 16);
}
__device__ __forceinline__ u32 packbf2(float a, float b) {
  return (u32)f2bf(a) | ((u32)f2bf(b) << 16);
}
__device__ __forceinline__ bf16x8 ldg8(const u16* p) {
  return __builtin_bit_cast(bf16x8, *(const i32x4*)p);
}
__device__ __forceinline__ void g2lds16(const void* g, void* l) {
  __builtin_amdgcn_global_load_lds((const __attribute__((address_space(1))) void*)g,
                                   (__attribute__((address_space(3))) void*)l, 16, 0, 0);
}
__device__ __forceinline__ float sigm(float x) { return 1.f / (1.f + __expf(-x)); }
__device__ __forceinline__ float tanh_f(float x) { return 2.f / (1.f + __expf(-2.f * x)) - 1.f; }

// ---------------------------------------------------------------------------
// prep kernels
// ---------------------------------------------------------------------------
__global__ void prep_x(const float* __restrict__ x, u16* __restrict__ xb) {
  size_t i = ((size_t)blockIdx.x * 256 + threadIdx.x) * 4;
  float4 v = *(const float4*)(x + i);
  *(uint2*)(xb + i) = make_uint2(packbf2(v.x, v.y), packbf2(v.z, v.w));
}

__global__ void prep_misc(
    const float* __restrict__ wihl, const float* __restrict__ whhl,
    const float* __restrict__ wihg, const float* __restrict__ whhg,
    const float* __restrict__ bihl, const float* __restrict__ bhhl,
    const float* __restrict__ fc1W, const float* __restrict__ fcoW,
    u16* __restrict__ wihlb, u16* __restrict__ whhlb,
    u16* __restrict__ wihgb, u16* __restrict__ whhgb,
    float* __restrict__ biasl, float* __restrict__ fc1Wt, float* __restrict__ fcoWt) {
  int i = blockIdx.x * 256 + threadIdx.x;
  if (i < 65536) {
    wihlb[i] = f2bf(wihl[i]);
  } else if (i < 131072) {
    int k = i - 65536; whhlb[k] = f2bf(whhl[k]);
  } else if (i < 180224) {
    int k = i - 131072; wihgb[k] = f2bf(wihg[k]);
  } else if (i < 229376) {
    int k = i - 180224; whhgb[k] = f2bf(whhg[k]);
  } else if (i < 229888) {
    int k = i - 229376; biasl[k] = bihl[k] + bhhl[k];
  } else if (i < 250368) {
    int k = i - 229888;                       // fc1Wt[g*160+f] = fc1W[f*128+g]
    fc1Wt[k] = fc1W[(k % 160) * 128 + (k / 160)];
  } else if (i < 260608) {
    int k = i - 250368;                       // fcoWt[f*64+c] = fcoW[c*160+f]
    fcoWt[k] = fcoW[(k % 64) * 160 + (k / 64)];
  }
}

// ---------------------------------------------------------------------------
// NT GEMM: C[M,N] bf16 = A[M,128] bf16 @ Bw[N,128]^T + bias[N]; tile 128x128
// ---------------------------------------------------------------------------
__global__ __launch_bounds__(256) void gemm_nt(
    const u16* __restrict__ A, const u16* __restrict__ Bw,
    const float* __restrict__ bias, u16* __restrict__ C, int N) {
  __shared__ __align__(16) u16 sA[128 * 128];
  __shared__ __align__(16) u16 sB[128 * 128];
  const int tid = threadIdx.x;
  const int w = tid >> 6, l = tid & 63;
  const size_t m0 = (size_t)blockIdx.x * 128;
  const int n0 = blockIdx.y * 128;
  const char* gA = (const char*)(A + m0 * 128);
  const char* gB = (const char*)(Bw + (size_t)n0 * 128);
  char* lA = (char*)sA;
  char* lB = (char*)sB;
#pragma unroll
  for (int i = 0; i < 8; i++) {
    int ubase = (w * 8 + i) << 10;   // 1KB per wave-inst
    int off = ubase + (l << 4);
    g2lds16(gA + off, lA + ubase);
    g2lds16(gB + off, lB + ubase);
  }
  __syncthreads();
  const int mq = (w >> 1) * 64, nq = (w & 1) * 64;
  f32x4 acc[4][4];
#pragma unroll
  for (int i = 0; i < 4; i++)
#pragma unroll
    for (int j = 0; j < 4; j++) acc[i][j] = (f32x4){0.f, 0.f, 0.f, 0.f};
#pragma unroll
  for (int k0 = 0; k0 < 4; k0++) {
    const int koff = k0 * 32 + (l >> 4) * 8;
    bf16x8 af[4], bf[4];
#pragma unroll
    for (int i = 0; i < 4; i++) af[i] = ldg8(&sA[(mq + i * 16 + (l & 15)) * 128 + koff]);
#pragma unroll
    for (int j = 0; j < 4; j++) bf[j] = ldg8(&sB[(nq + j * 16 + (l & 15)) * 128 + koff]);
#pragma unroll
    for (int i = 0; i < 4; i++)
#pragma unroll
      for (int j = 0; j < 4; j++)
        acc[i][j] = __builtin_amdgcn_mfma_f32_16x16x32_bf16(af[i], bf[j], acc[i][j], 0, 0, 0);
  }
  float bv[4];
#pragma unroll
  for (int j = 0; j < 4; j++) bv[j] = bias[n0 + nq + j * 16 + (l & 15)];
  __syncthreads();
  u16* sOut = sA;  // reuse
#pragma unroll
  for (int i = 0; i < 4; i++)
#pragma unroll
    for (int j = 0; j < 4; j++)
#pragma unroll
      for (int r = 0; r < 4; r++)
        sOut[(mq + i * 16 + (l >> 4) * 4 + r) * 128 + nq + j * 16 + (l & 15)] =
            f2bf(acc[i][j][r] + bv[j]);
  __syncthreads();
#pragma unroll
  for (int p = 0; p < 8; p++) {
    int e = (p * 256 + tid) * 8;  // element index within 128x128 tile
    int row = e >> 7, col = e & 127;
    *(i32x4*)(C + (m0 + row) * (size_t)N + n0 + col) = *(const i32x4*)&sOut[e];
  }
}

// ---------------------------------------------------------------------------
// LSTM scan, gates in C-layout registers. 32 blocks x 512 thr; 16 batch/block.
// Wave w owns hidden cols [w*16, w*16+16); its 4 MFMA N-tiles are the 4 gates
// at cols {g*128 + w*16}. i/f/g/o for one (row,col) land in one lane/reg.
// ---------------------------------------------------------------------------
__global__ __launch_bounds__(512) void lstm_scan(
    const u16* __restrict__ gx,   // [BT][512] bf16 (x-proj + bih + bhh)
    const u16* __restrict__ whh,  // [512][128] bf16
    u16* __restrict__ lout) {     // [B][T][128] bf16, RAW h (LN applied later)
  const int tid = threadIdx.x;
  const int w = tid >> 6, l = tid & 63;
  const int hc = l & 15, q = l >> 4;
  const int col = w * 16 + hc;          // hidden col owned by this lane
  const int b0 = blockIdx.x * 16;
  __shared__ __align__(16) u16 hb0[16 * 136];
  __shared__ __align__(16) u16 hb1[16 * 136];

  // persistent Whh B-fragments: wf[g][k0] covers cols g*128 + w*16 + hc
  bf16x8 wf[4][4];
#pragma unroll
  for (int g = 0; g < 4; g++)
#pragma unroll
    for (int k0 = 0; k0 < 4; k0++)
      wf[g][k0] = ldg8(&whh[(g * 128 + col) * 128 + k0 * 32 + q * 8]);

  float c[4] = {0.f, 0.f, 0.f, 0.f};
  size_t rb[4], lb[4];
#pragma unroll
  for (int r = 0; r < 4; r++) {
    int b = b0 + q * 4 + r;
    rb[r] = (size_t)b * TT * 512 + col;   // gx base for this lane-row
    lb[r] = (size_t)b * TT * 128 + col;   // lout base
  }
  for (int i = tid; i < 16 * 136; i += 512) hb0[i] = 0;

  u16 ga[16], gb[16];
#pragma unroll
  for (int r = 0; r < 4; r++) {
    const u16* p = gx + rb[r];
#pragma unroll
    for (int g = 0; g < 4; g++) ga[g * 4 + r] = p[g * 128];
  }
  __syncthreads();

  auto step = [&](int t, u16 (&gc)[16], u16 (&gp)[16], const u16* hrd, u16* hwr) {
    // prefetch t+1 (latency overlapped with the whole step)
    int tn = (t + 1 < TT) ? (t + 1) : t;
#pragma unroll
    for (int r = 0; r < 4; r++) {
      const u16* p = gx + rb[r] + (size_t)tn * 512;
#pragma unroll
      for (int g = 0; g < 4; g++) gp[g * 4 + r] = p[g * 128];
    }
    // h_prev @ Whh^T
    bf16x8 af[4];
#pragma unroll
    for (int k0 = 0; k0 < 4; k0++)
      af[k0] = ldg8(&hrd[hc * 136 + k0 * 32 + q * 8]);
    f32x4 acc[4];
#pragma unroll
    for (int g = 0; g < 4; g++) acc[g] = (f32x4){0.f, 0.f, 0.f, 0.f};
#pragma unroll
    for (int k0 = 0; k0 < 4; k0++)
#pragma unroll
      for (int g = 0; g < 4; g++)
        acc[g] = __builtin_amdgcn_mfma_f32_16x16x32_bf16(af[k0], wf[g][k0], acc[g], 0, 0, 0);
    // gates — entirely in-register
#pragma unroll
    for (int r = 0; r < 4; r++) {
      float pi = acc[0][r] + bf2f(gc[0 * 4 + r]);
      float pf = acc[1][r] + bf2f(gc[1 * 4 + r]);
      float pg = acc[2][r] + bf2f(gc[2 * 4 + r]);
      float po = acc[3][r] + bf2f(gc[3 * 4 + r]);
      c[r] = sigm(pf) * c[r] + sigm(pi) * tanh_f(pg);
      float h = sigm(po) * tanh_f(c[r]);
      u16 hv = f2bf(h);
      hwr[(q * 4 + r) * 136 + col] = hv;
      lout[lb[r] + (size_t)t * 128] = hv;
    }
    __syncthreads();
  };

#pragma unroll 1
  for (int t2 = 0; t2 < TT; t2 += 2) {
    if ((t2 & 2) == 0) { step(t2, ga, gb, hb0, hb1); step(t2 + 1, gb, ga, hb1, hb0); }
    else               { step(t2, ga, gb, hb0, hb1); step(t2 + 1, gb, ga, hb1, hb0); }
  }
}

// ---------------------------------------------------------------------------
// In-place row LayerNorm over [BT][128] bf16. One wave per row.
// ---------------------------------------------------------------------------
__global__ __launch_bounds__(256) void ln_pass(
    u16* __restrict__ buf, const float* __restrict__ g, const float* __restrict__ b) {
  const size_t row = (size_t)blockIdx.x * 4 + (threadIdx.x >> 6);
  const int l = threadIdx.x & 63;
  u16* p = buf + row * 128 + l * 2;
  u32 v = *(const u32*)p;
  float a0 = bf2f((u16)v), a1 = bf2f((u16)(v >> 16));
  float s1 = a0 + a1, s2 = a0 * a0 + a1 * a1;
#pragma unroll
  for (int m = 1; m < 64; m <<= 1) { s1 += __shfl_xor(s1, m); s2 += __shfl_xor(s2, m); }
  float mean = s1 * 0.0078125f;
  float var = s2 * 0.0078125f - mean * mean;
  float rs = rsqrtf(var + 1e-5f);
  float2 gg = *(const float2*)(g + l * 2);
  float2 bb = *(const float2*)(b + l * 2);
  float y0 = (a0 - mean) * rs * gg.x + bb.x;
  float y1 = (a1 - mean) * rs * gg.y + bb.y;
  *(u32*)p = packbf2(y0, y1);
}

// ---------------------------------------------------------------------------
// GRU scan -> final hidden only. Same C-layout register scheme, 3 gates.
// ---------------------------------------------------------------------------
__global__ __launch_bounds__(512) void gru_scan(
    const u16* __restrict__ gx,   // [BT][384] bf16 (x-proj + bih)
    const u16* __restrict__ whh,  // [384][128] bf16
    const float* __restrict__ bhh,
    float* __restrict__ hlast) {  // [512][128] fp32
  const int tid = threadIdx.x;
  const int w = tid >> 6, l = tid & 63;
  const int hc = l & 15, q = l >> 4;
  const int col = w * 16 + hc;
  const int b0 = blockIdx.x * 16;
  __shared__ __align__(16) u16 hb0[16 * 136];
  __shared__ __align__(16) u16 hb1[16 * 136];

  bf16x8 wf[3][4];
#pragma unroll
  for (int g = 0; g < 3; g++)
#pragma unroll
    for (int k0 = 0; k0 < 4; k0++)
      wf[g][k0] = ldg8(&whh[(g * 128 + col) * 128 + k0 * 32 + q * 8]);

  const float bhr = bhh[col], bhz = bhh[128 + col], bhn = bhh[256 + col];
  float hp[4] = {0.f, 0.f, 0.f, 0.f};
  size_t rb[4];
#pragma unroll
  for (int r = 0; r < 4; r++) rb[r] = (size_t)(b0 + q * 4 + r) * TT * 384 + col;
  for (int i = tid; i < 16 * 136; i += 512) hb0[i] = 0;

  u16 ga[12], gb[12];
#pragma unroll
  for (int r = 0; r < 4; r++) {
    const u16* p = gx + rb[r];
#pragma unroll
    for (int g = 0; g < 3; g++) ga[g * 4 + r] = p[g * 128];
  }
  __syncthreads();

  auto step = [&](int t, u16 (&gc)[12], u16 (&gp)[12], const u16* hrd, u16* hwr) {
    int tn = (t + 1 < TT) ? (t + 1) : t;
#pragma unroll
    for (int r = 0; r < 4; r++) {
      const u16* p = gx + rb[r] + (size_t)tn * 384;
#pragma unroll
      for (int g = 0; g < 3; g++) gp[g * 4 + r] = p[g * 128];
    }
    bf16x8 af[4];
#pragma unroll
    for (int k0 = 0; k0 < 4; k0++)
      af[k0] = ldg8(&hrd[hc * 136 + k0 * 32 + q * 8]);
    f32x4 acc[3];
#pragma unroll
    for (int g = 0; g < 3; g++) acc[g] = (f32x4){0.f, 0.f, 0.f, 0.f};
#pragma unroll
    for (int k0 = 0; k0 < 4; k0++)
#pragma unroll
      for (int g = 0; g < 3; g++)
        acc[g] = __builtin_amdgcn_mfma_f32_16x16x32_bf16(af[k0], wf[g][k0], acc[g], 0, 0, 0);
#pragma unroll
    for (int r = 0; r < 4; r++) {
      float rr = sigm(bf2f(gc[0 * 4 + r]) + acc[0][r] + bhr);
      float zz = sigm(bf2f(gc[1 * 4 + r]) + acc[1][r] + bhz);
      float nn = tanh_f(bf2f(gc[2 * 4 + r]) + rr * (acc[2][r] + bhn));
      hp[r] = nn + zz * (hp[r] - nn);
      hwr[(q * 4 + r) * 136 + col] = f2bf(hp[r]);
    }
    __syncthreads();
  };

#pragma unroll 1
  for (int t2 = 0; t2 < TT; t2 += 2) {
    step(t2, ga, gb, hb0, hb1);
    step(t2 + 1, gb, ga, hb1, hb0);
  }
#pragma unroll
  for (int r = 0; r < 4; r++)
    hlast[(size_t)(b0 + q * 4 + r) * 128 + col] = hp[r];
}

// ---------------------------------------------------------------------------
// Head: LN(gru) -> relu -> fc1 -> LN(fc1) -> relu -> fco. One block per row.
// ---------------------------------------------------------------------------
__global__ __launch_bounds__(256) void head(
    const float* __restrict__ hlast,
    const float* __restrict__ g1, const float* __restrict__ b1,
    const float* __restrict__ fc1Wt, const float* __restrict__ fc1b,
    const float* __restrict__ g2, const float* __restrict__ b2,
    const float* __restrict__ fcoWt, const float* __restrict__ fcob,
    float* __restrict__ out) {
  const int b = blockIdx.x, tid = threadIdx.x;
  __shared__ float yv[128];
  __shared__ float zv[160];
  __shared__ float red[8];
  float v = (tid < 128) ? hlast[b * 128 + tid] : 0.f;
  float p1 = v, p2 = v * v;
#pragma unroll
  for (int m = 1; m < 64; m <<= 1) { p1 += __shfl_xor(p1, m); p2 += __shfl_xor(p2, m); }
  if ((tid & 63) == 0) { red[(tid >> 6) * 2] = p1; red[(tid >> 6) * 2 + 1] = p2; }
  __syncthreads();
  float s1 = red[0] + red[2] + red[4] + red[6];
  float s2 = red[1] + red[3] + red[5] + red[7];
  float mean = s1 * (1.f / 128.f);
  float var = s2 * (1.f / 128.f) - mean * mean;
  float rs = rsqrtf(var + 1e-5f);
  if (tid < 128) yv[tid] = fmaxf((v - mean) * rs * g1[tid] + b1[tid], 0.f);
  __syncthreads();
  float z = 0.f;
  if (tid < 160) {
    z = fc1b[tid];
    for (int g = 0; g < 128; g++) z += yv[g] * fc1Wt[g * 160 + tid];
  }
  float q1 = (tid < 160) ? z : 0.f;
  float q2 = (tid < 160) ? z * z : 0.f;
#pragma unroll
  for (int m = 1; m < 64; m <<= 1) { q1 += __shfl_xor(q1, m); q2 += __shfl_xor(q2, m); }
  __syncthreads();
  if ((tid & 63) == 0) { red[(tid >> 6) * 2] = q1; red[(tid >> 6) * 2 + 1] = q2; }
  __syncthreads();
  s1 = red[0] + red[2] + red[4] + red[6];
  s2 = red[1] + red[3] + red[5] + red[7];
  mean = s1 * (1.f / 160.f);
  var = s2 * (1.f / 160.f) - mean * mean;
  rs = rsqrtf(var + 1e-5f);
  if (tid < 160) zv[tid] = fmaxf((z - mean) * rs * g2[tid] + b2[tid], 0.f);
  __syncthreads();
  if (tid < 64) {
    float o = fcob[tid];
    for (int f = 0; f < 160; f++) o += zv[f] * fcoWt[f * 64 + tid];
    out[b * 64 + tid] = o;
  }
}

// ---------------------------------------------------------------------------
// workspace layout (bytes) — total ~404 MB; gx region shared by LSTM/GRU phases
// ---------------------------------------------------------------------------
static constexpr size_t OFF_XBF   = 0;                          // 67,108,864
static constexpr size_t OFF_GX    = 67108864;                   // 268,435,456
static constexpr size_t OFF_LOUT  = OFF_GX + 268435456;         // 67,108,864
static constexpr size_t OFF_WIHL  = OFF_LOUT + 67108864;        // 131,072
static constexpr size_t OFF_WHHL  = OFF_WIHL + 131072;          // 131,072
static constexpr size_t OFF_WIHG  = OFF_WHHL + 131072;          // 98,304
static constexpr size_t OFF_WHHG  = OFF_WIHG + 98304;           // 98,304
static constexpr size_t OFF_BIASL = OFF_WHHG + 98304;           // 2,048
static constexpr size_t OFF_FC1T  = OFF_BIASL + 2048;           // 81,920
static constexpr size_t OFF_FCOT  = OFF_FC1T + 81920;           // 40,960
static constexpr size_t OFF_HLAST = OFF_FCOT + 40960;           // 262,144

extern "C" void kernel_launch(void* const* d_in, const int* in_sizes, int n_in,
                              void* d_out, int out_size, void* d_ws, size_t ws_size,
                              hipStream_t stream) {
  (void)in_sizes; (void)n_in; (void)out_size; (void)ws_size;
  const float* x    = (const float*)d_in[0];
  const float* lWih = (const float*)d_in[1];
  const float* lWhh = (const float*)d_in[2];
  const float* lbih = (const float*)d_in[3];
  const float* lbhh = (const float*)d_in[4];
  const float* gWih = (const float*)d_in[5];
  const float* gWhh = (const float*)d_in[6];
  const float* gbih = (const float*)d_in[7];
  const float* gbhh = (const float*)d_in[8];
  const float* lnLg = (const float*)d_in[9];
  const float* lnLb = (const float*)d_in[10];
  const float* lnGg = (const float*)d_in[11];
  const float* lnGb = (const float*)d_in[12];
  const float* fc1W = (const float*)d_in[13];
  const float* fc1b = (const float*)d_in[14];
  const float* lnFg = (const float*)d_in[15];
  const float* lnFb = (const float*)d_in[16];
  const float* fcoW = (const float*)d_in[17];
  const float* fcob = (const float*)d_in[18];

  char* ws = (char*)d_ws;
  u16* xbf    = (u16*)(ws + OFF_XBF);
  u16* gx     = (u16*)(ws + OFF_GX);
  u16* lout   = (u16*)(ws + OFF_LOUT);
  u16* wihlb  = (u16*)(ws + OFF_WIHL);
  u16* whhlb  = (u16*)(ws + OFF_WHHL);
  u16* wihgb  = (u16*)(ws + OFF_WIHG);
  u16* whhgb  = (u16*)(ws + OFF_WHHG);
  float* biasl = (float*)(ws + OFF_BIASL);
  float* fc1Wt = (float*)(ws + OFF_FC1T);
  float* fcoWt = (float*)(ws + OFF_FCOT);
  float* hlast = (float*)(ws + OFF_HLAST);
  float* out   = (float*)d_out;

  prep_x<<<32768, 256, 0, stream>>>(x, xbf);
  prep_misc<<<1024, 256, 0, stream>>>(lWih, lWhh, gWih, gWhh, lbih, lbhh, fc1W, fcoW,
                                      wihlb, whhlb, wihgb, whhgb, biasl, fc1Wt, fcoWt);
  gemm_nt<<<dim3(2048, 4), 256, 0, stream>>>(xbf, wihlb, biasl, gx, 512);
  lstm_scan<<<32, 512, 0, stream>>>(gx, whhlb, lout);
  ln_pass<<<65536, 256, 0, stream>>>(lout, lnLg, lnLb);
  gemm_nt<<<dim3(2048, 3), 256, 0, stream>>>(lout, wihgb, gbih, gx, 384);
  gru_scan<<<32, 512, 0, stream>>>(gx, whhgb, gbhh, hlast);
  head<<<512, 256, 0, stream>>>(hlast, lnGg, lnGb, fc1Wt, fc1b, lnFg, lnFb, fcoWt, fcob, out);
}

// Round 3
// 1378.681 us; speedup vs baseline: 1.5992x; 1.5992x over previous
//
#include <hip/hip_runtime.h>

// ---------------------------------------------------------------------------
// LSTMGRUHybrid: B=512, T=512, D=128, H=128 (4H=512), G=128 (3G=384), F=160, C=64
// Round 3: scans are VALU-bound (65% active-CU VALUBusy). Kill IEEE division
// sequences (rcpf), 32-bit saddr+voffset addressing, lgkm-only barrier.
// ---------------------------------------------------------------------------

typedef __attribute__((ext_vector_type(8))) short bf16x8;
typedef __attribute__((ext_vector_type(4))) float f32x4;
typedef __attribute__((ext_vector_type(4))) int i32x4;
typedef unsigned short u16;
typedef unsigned int u32;

#define BT 262144          // B*T
#define TT 512

__device__ __forceinline__ u16 f2bf(float f) {
  u32 u = __builtin_bit_cast(u32, f);
  u += 0x7fffu + ((u >> 16) & 1u);
  return (u16)(u >> 16);
}
__device__ __forceinline__ float bf2f(u16 h) {
  return __builtin_bit_cast(float, (u32)h << 16);
}
__device__ __forceinline__ u32 packbf2(float a, float b) {
  return (u32)f2bf(a) | ((u32)f2bf(b) << 16);
}
__device__ __forceinline__ bf16x8 ldg8(const u16* p) {
  return __builtin_bit_cast(bf16x8, *(const i32x4*)p);
}
__device__ __forceinline__ void g2lds16(const void* g, void* l) {
  __builtin_amdgcn_global_load_lds((const __attribute__((address_space(1))) void*)g,
                                   (__attribute__((address_space(3))) void*)l, 16, 0, 0);
}
// fast sigmoid/tanh: v_rcp instead of IEEE div sequence (~12-20 insts each)
__device__ __forceinline__ float frcp(float x) { return __builtin_amdgcn_rcpf(x); }
__device__ __forceinline__ float sigm(float x) { return frcp(1.f + __expf(-x)); }
__device__ __forceinline__ float tanh_f(float x) {
  return 1.f - 2.f * frcp(__expf(2.f * x) + 1.f);
}
// barrier that only drains LDS (not vmcnt) — keeps gx prefetch / lout stores
// off the per-step critical path. 0xC07F = vmcnt(63) expcnt(7) lgkmcnt(0).
__device__ __forceinline__ void scan_barrier() {
  __asm__ volatile("" ::: "memory");
  __builtin_amdgcn_s_waitcnt(0xC07F);
  __builtin_amdgcn_s_barrier();
  __asm__ volatile("" ::: "memory");
}

// ---------------------------------------------------------------------------
// prep kernels
// ---------------------------------------------------------------------------
__global__ void prep_x(const float* __restrict__ x, u16* __restrict__ xb) {
  size_t i = ((size_t)blockIdx.x * 256 + threadIdx.x) * 4;
  float4 v = *(const float4*)(x + i);
  *(uint2*)(xb + i) = make_uint2(packbf2(v.x, v.y), packbf2(v.z, v.w));
}

__global__ void prep_misc(
    const float* __restrict__ wihl, const float* __restrict__ whhl,
    const float* __restrict__ wihg, const float* __restrict__ whhg,
    const float* __restrict__ bihl, const float* __restrict__ bhhl,
    const float* __restrict__ fc1W, const float* __restrict__ fcoW,
    u16* __restrict__ wihlb, u16* __restrict__ whhlb,
    u16* __restrict__ wihgb, u16* __restrict__ whhgb,
    float* __restrict__ biasl, float* __restrict__ fc1Wt, float* __restrict__ fcoWt) {
  int i = blockIdx.x * 256 + threadIdx.x;
  if (i < 65536) {
    wihlb[i] = f2bf(wihl[i]);
  } else if (i < 131072) {
    int k = i - 65536; whhlb[k] = f2bf(whhl[k]);
  } else if (i < 180224) {
    int k = i - 131072; wihgb[k] = f2bf(wihg[k]);
  } else if (i < 229376) {
    int k = i - 180224; whhgb[k] = f2bf(whhg[k]);
  } else if (i < 229888) {
    int k = i - 229376; biasl[k] = bihl[k] + bhhl[k];
  } else if (i < 250368) {
    int k = i - 229888;                       // fc1Wt[g*160+f] = fc1W[f*128+g]
    fc1Wt[k] = fc1W[(k % 160) * 128 + (k / 160)];
  } else if (i < 260608) {
    int k = i - 250368;                       // fcoWt[f*64+c] = fcoW[c*160+f]
    fcoWt[k] = fcoW[(k % 64) * 160 + (k / 64)];
  }
}

// ---------------------------------------------------------------------------
// NT GEMM: C[M,N] bf16 = A[M,128] bf16 @ Bw[N,128]^T + bias[N]; tile 128x128
// ---------------------------------------------------------------------------
__global__ __launch_bounds__(256) void gemm_nt(
    const u16* __restrict__ A, const u16* __restrict__ Bw,
    const float* __restrict__ bias, u16* __restrict__ C, int N) {
  __shared__ __align__(16) u16 sA[128 * 128];
  __shared__ __align__(16) u16 sB[128 * 128];
  const int tid = threadIdx.x;
  const int w = tid >> 6, l = tid & 63;
  const size_t m0 = (size_t)blockIdx.x * 128;
  const int n0 = blockIdx.y * 128;
  const char* gA = (const char*)(A + m0 * 128);
  const char* gB = (const char*)(Bw + (size_t)n0 * 128);
  char* lA = (char*)sA;
  char* lB = (char*)sB;
#pragma unroll
  for (int i = 0; i < 8; i++) {
    int ubase = (w * 8 + i) << 10;   // 1KB per wave-inst
    int off = ubase + (l << 4);
    g2lds16(gA + off, lA + ubase);
    g2lds16(gB + off, lB + ubase);
  }
  __syncthreads();
  const int mq = (w >> 1) * 64, nq = (w & 1) * 64;
  f32x4 acc[4][4];
#pragma unroll
  for (int i = 0; i < 4; i++)
#pragma unroll
    for (int j = 0; j < 4; j++) acc[i][j] = (f32x4){0.f, 0.f, 0.f, 0.f};
#pragma unroll
  for (int k0 = 0; k0 < 4; k0++) {
    const int koff = k0 * 32 + (l >> 4) * 8;
    bf16x8 af[4], bf[4];
#pragma unroll
    for (int i = 0; i < 4; i++) af[i] = ldg8(&sA[(mq + i * 16 + (l & 15)) * 128 + koff]);
#pragma unroll
    for (int j = 0; j < 4; j++) bf[j] = ldg8(&sB[(nq + j * 16 + (l & 15)) * 128 + koff]);
#pragma unroll
    for (int i = 0; i < 4; i++)
#pragma unroll
      for (int j = 0; j < 4; j++)
        acc[i][j] = __builtin_amdgcn_mfma_f32_16x16x32_bf16(af[i], bf[j], acc[i][j], 0, 0, 0);
  }
  float bv[4];
#pragma unroll
  for (int j = 0; j < 4; j++) bv[j] = bias[n0 + nq + j * 16 + (l & 15)];
  __syncthreads();
  u16* sOut = sA;  // reuse
#pragma unroll
  for (int i = 0; i < 4; i++)
#pragma unroll
    for (int j = 0; j < 4; j++)
#pragma unroll
      for (int r = 0; r < 4; r++)
        sOut[(mq + i * 16 + (l >> 4) * 4 + r) * 128 + nq + j * 16 + (l & 15)] =
            f2bf(acc[i][j][r] + bv[j]);
  __syncthreads();
#pragma unroll
  for (int p = 0; p < 8; p++) {
    int e = (p * 256 + tid) * 8;  // element index within 128x128 tile
    int row = e >> 7, col = e & 127;
    *(i32x4*)(C + (m0 + row) * (size_t)N + n0 + col) = *(const i32x4*)&sOut[e];
  }
}

// ---------------------------------------------------------------------------
// LSTM scan, gates in C-layout registers. 32 blocks x 512 thr; 16 batch/block.
// Wave w owns hidden cols [w*16, w*16+16); its 4 MFMA N-tiles are the 4 gates.
// ---------------------------------------------------------------------------
__global__ __launch_bounds__(512) void lstm_scan(
    const u16* __restrict__ gx,   // [BT][512] bf16 (x-proj + bih + bhh)
    const u16* __restrict__ whh,  // [512][128] bf16
    u16* __restrict__ lout) {     // [B][T][128] bf16, RAW h (LN applied later)
  const int tid = threadIdx.x;
  const int w = tid >> 6, l = tid & 63;
  const int hc = l & 15, q = l >> 4;
  const int col = w * 16 + hc;
  const int b0 = blockIdx.x * 16;
  __shared__ __align__(16) u16 hb0[16 * 136];
  __shared__ __align__(16) u16 hb1[16 * 136];

  bf16x8 wf[4][4];
#pragma unroll
  for (int g = 0; g < 4; g++)
#pragma unroll
    for (int k0 = 0; k0 < 4; k0++)
      wf[g][k0] = ldg8(&whh[(g * 128 + col) * 128 + k0 * 32 + q * 8]);

  float c[4] = {0.f, 0.f, 0.f, 0.f};
  u32 goff[4], loff[4];   // 32-bit element offsets -> saddr+voffset addressing
#pragma unroll
  for (int r = 0; r < 4; r++) {
    u32 b = b0 + q * 4 + r;
    goff[r] = b * (TT * 512) + col;
    loff[r] = b * (TT * 128) + col;
  }
  for (int i = tid; i < 16 * 136; i += 512) hb0[i] = 0;

  u16 ga[16], gb[16];
#pragma unroll
  for (int r = 0; r < 4; r++)
#pragma unroll
    for (int g = 0; g < 4; g++) ga[g * 4 + r] = gx[goff[r] + g * 128];
#pragma unroll
  for (int r = 0; r < 4; r++) goff[r] += 512;
  scan_barrier();

  auto step = [&](u16 (&gc)[16], u16 (&gp)[16], const u16* hrd, u16* hwr) {
    // prefetch t+1 (vmcnt NOT drained at barrier; lands by next gate phase)
#pragma unroll
    for (int r = 0; r < 4; r++)
#pragma unroll
      for (int g = 0; g < 4; g++) gp[g * 4 + r] = gx[goff[r] + g * 128];
#pragma unroll
    for (int r = 0; r < 4; r++) goff[r] += 512;
    // h_prev @ Whh^T
    bf16x8 af[4];
#pragma unroll
    for (int k0 = 0; k0 < 4; k0++)
      af[k0] = ldg8(&hrd[hc * 136 + k0 * 32 + q * 8]);
    f32x4 acc[4];
#pragma unroll
    for (int g = 0; g < 4; g++) acc[g] = (f32x4){0.f, 0.f, 0.f, 0.f};
#pragma unroll
    for (int k0 = 0; k0 < 4; k0++)
#pragma unroll
      for (int g = 0; g < 4; g++)
        acc[g] = __builtin_amdgcn_mfma_f32_16x16x32_bf16(af[k0], wf[g][k0], acc[g], 0, 0, 0);
    // gates — in-register, rcp-based sigmoid/tanh
#pragma unroll
    for (int r = 0; r < 4; r++) {
      float pi = acc[0][r] + bf2f(gc[0 * 4 + r]);
      float pf = acc[1][r] + bf2f(gc[1 * 4 + r]);
      float pg = acc[2][r] + bf2f(gc[2 * 4 + r]);
      float po = acc[3][r] + bf2f(gc[3 * 4 + r]);
      c[r] = sigm(pf) * c[r] + sigm(pi) * tanh_f(pg);
      float h = sigm(po) * tanh_f(c[r]);
      u16 hv = f2bf(h);
      hwr[(q * 4 + r) * 136 + col] = hv;
      lout[loff[r]] = hv;
    }
#pragma unroll
    for (int r = 0; r < 4; r++) loff[r] += 128;
    scan_barrier();
  };

#pragma unroll 1
  for (int t2 = 0; t2 < TT; t2 += 2) {
    step(ga, gb, hb0, hb1);
    step(gb, ga, hb1, hb0);
  }
}

// ---------------------------------------------------------------------------
// In-place row LayerNorm over [BT][128] bf16. One wave per row.
// ---------------------------------------------------------------------------
__global__ __launch_bounds__(256) void ln_pass(
    u16* __restrict__ buf, const float* __restrict__ g, const float* __restrict__ b) {
  const size_t row = (size_t)blockIdx.x * 4 + (threadIdx.x >> 6);
  const int l = threadIdx.x & 63;
  u16* p = buf + row * 128 + l * 2;
  u32 v = *(const u32*)p;
  float a0 = bf2f((u16)v), a1 = bf2f((u16)(v >> 16));
  float s1 = a0 + a1, s2 = a0 * a0 + a1 * a1;
#pragma unroll
  for (int m = 1; m < 64; m <<= 1) { s1 += __shfl_xor(s1, m); s2 += __shfl_xor(s2, m); }
  float mean = s1 * 0.0078125f;
  float var = s2 * 0.0078125f - mean * mean;
  float rs = rsqrtf(var + 1e-5f);
  float2 gg = *(const float2*)(g + l * 2);
  float2 bb = *(const float2*)(b + l * 2);
  float y0 = (a0 - mean) * rs * gg.x + bb.x;
  float y1 = (a1 - mean) * rs * gg.y + bb.y;
  *(u32*)p = packbf2(y0, y1);
}

// ---------------------------------------------------------------------------
// GRU scan -> final hidden only. Same C-layout register scheme, 3 gates.
// ---------------------------------------------------------------------------
__global__ __launch_bounds__(512) void gru_scan(
    const u16* __restrict__ gx,   // [BT][384] bf16 (x-proj + bih)
    const u16* __restrict__ whh,  // [384][128] bf16
    const float* __restrict__ bhh,
    float* __restrict__ hlast) {  // [512][128] fp32
  const int tid = threadIdx.x;
  const int w = tid >> 6, l = tid & 63;
  const int hc = l & 15, q = l >> 4;
  const int col = w * 16 + hc;
  const int b0 = blockIdx.x * 16;
  __shared__ __align__(16) u16 hb0[16 * 136];
  __shared__ __align__(16) u16 hb1[16 * 136];

  bf16x8 wf[3][4];
#pragma unroll
  for (int g = 0; g < 3; g++)
#pragma unroll
    for (int k0 = 0; k0 < 4; k0++)
      wf[g][k0] = ldg8(&whh[(g * 128 + col) * 128 + k0 * 32 + q * 8]);

  const float bhr = bhh[col], bhz = bhh[128 + col], bhn = bhh[256 + col];
  float hp[4] = {0.f, 0.f, 0.f, 0.f};
  u32 goff[4];
#pragma unroll
  for (int r = 0; r < 4; r++) goff[r] = (u32)(b0 + q * 4 + r) * (TT * 384) + col;
  for (int i = tid; i < 16 * 136; i += 512) hb0[i] = 0;

  u16 ga[12], gb[12];
#pragma unroll
  for (int r = 0; r < 4; r++)
#pragma unroll
    for (int g = 0; g < 3; g++) ga[g * 4 + r] = gx[goff[r] + g * 128];
#pragma unroll
  for (int r = 0; r < 4; r++) goff[r] += 384;
  scan_barrier();

  auto step = [&](u16 (&gc)[12], u16 (&gp)[12], const u16* hrd, u16* hwr) {
#pragma unroll
    for (int r = 0; r < 4; r++)
#pragma unroll
      for (int g = 0; g < 3; g++) gp[g * 4 + r] = gx[goff[r] + g * 128];
#pragma unroll
    for (int r = 0; r < 4; r++) goff[r] += 384;
    bf16x8 af[4];
#pragma unroll
    for (int k0 = 0; k0 < 4; k0++)
      af[k0] = ldg8(&hrd[hc * 136 + k0 * 32 + q * 8]);
    f32x4 acc[3];
#pragma unroll
    for (int g = 0; g < 3; g++) acc[g] = (f32x4){0.f, 0.f, 0.f, 0.f};
#pragma unroll
    for (int k0 = 0; k0 < 4; k0++)
#pragma unroll
      for (int g = 0; g < 3; g++)
        acc[g] = __builtin_amdgcn_mfma_f32_16x16x32_bf16(af[k0], wf[g][k0], acc[g], 0, 0, 0);
#pragma unroll
    for (int r = 0; r < 4; r++) {
      float rr = sigm(bf2f(gc[0 * 4 + r]) + acc[0][r] + bhr);
      float zz = sigm(bf2f(gc[1 * 4 + r]) + acc[1][r] + bhz);
      float nn = tanh_f(bf2f(gc[2 * 4 + r]) + rr * (acc[2][r] + bhn));
      hp[r] = nn + zz * (hp[r] - nn);
      hwr[(q * 4 + r) * 136 + col] = f2bf(hp[r]);
    }
    scan_barrier();
  };

#pragma unroll 1
  for (int t2 = 0; t2 < TT; t2 += 2) {
    step(ga, gb, hb0, hb1);
    step(gb, ga, hb1, hb0);
  }
#pragma unroll
  for (int r = 0; r < 4; r++)
    hlast[(size_t)(b0 + q * 4 + r) * 128 + col] = hp[r];
}

// ---------------------------------------------------------------------------
// Head: LN(gru) -> relu -> fc1 -> LN(fc1) -> relu -> fco. One block per row.
// ---------------------------------------------------------------------------
__global__ __launch_bounds__(256) void head(
    const float* __restrict__ hlast,
    const float* __restrict__ g1, const float* __restrict__ b1,
    const float* __restrict__ fc1Wt, const float* __restrict__ fc1b,
    const float* __restrict__ g2, const float* __restrict__ b2,
    const float* __restrict__ fcoWt, const float* __restrict__ fcob,
    float* __restrict__ out) {
  const int b = blockIdx.x, tid = threadIdx.x;
  __shared__ float yv[128];
  __shared__ float zv[160];
  __shared__ float red[8];
  float v = (tid < 128) ? hlast[b * 128 + tid] : 0.f;
  float p1 = v, p2 = v * v;
#pragma unroll
  for (int m = 1; m < 64; m <<= 1) { p1 += __shfl_xor(p1, m); p2 += __shfl_xor(p2, m); }
  if ((tid & 63) == 0) { red[(tid >> 6) * 2] = p1; red[(tid >> 6) * 2 + 1] = p2; }
  __syncthreads();
  float s1 = red[0] + red[2] + red[4] + red[6];
  float s2 = red[1] + red[3] + red[5] + red[7];
  float mean = s1 * (1.f / 128.f);
  float var = s2 * (1.f / 128.f) - mean * mean;
  float rs = rsqrtf(var + 1e-5f);
  if (tid < 128) yv[tid] = fmaxf((v - mean) * rs * g1[tid] + b1[tid], 0.f);
  __syncthreads();
  float z = 0.f;
  if (tid < 160) {
    z = fc1b[tid];
    for (int g = 0; g < 128; g++) z += yv[g] * fc1Wt[g * 160 + tid];
  }
  float q1 = (tid < 160) ? z : 0.f;
  float q2 = (tid < 160) ? z * z : 0.f;
#pragma unroll
  for (int m = 1; m < 64; m <<= 1) { q1 += __shfl_xor(q1, m); q2 += __shfl_xor(q2, m); }
  __syncthreads();
  if ((tid & 63) == 0) { red[(tid >> 6) * 2] = q1; red[(tid >> 6) * 2 + 1] = q2; }
  __syncthreads();
  s1 = red[0] + red[2] + red[4] + red[6];
  s2 = red[1] + red[3] + red[5] + red[7];
  mean = s1 * (1.f / 160.f);
  var = s2 * (1.f / 160.f) - mean * mean;
  rs = rsqrtf(var + 1e-5f);
  if (tid < 160) zv[tid] = fmaxf((z - mean) * rs * g2[tid] + b2[tid], 0.f);
  __syncthreads();
  if (tid < 64) {
    float o = fcob[tid];
    for (int f = 0; f < 160; f++) o += zv[f] * fcoWt[f * 64 + tid];
    out[b * 64 + tid] = o;
  }
}

// ---------------------------------------------------------------------------
// workspace layout (bytes) — total ~404 MB; gx region shared by LSTM/GRU phases
// ---------------------------------------------------------------------------
static constexpr size_t OFF_XBF   = 0;                          // 67,108,864
static constexpr size_t OFF_GX    = 67108864;                   // 268,435,456
static constexpr size_t OFF_LOUT  = OFF_GX + 268435456;         // 67,108,864
static constexpr size_t OFF_WIHL  = OFF_LOUT + 67108864;        // 131,072
static constexpr size_t OFF_WHHL  = OFF_WIHL + 131072;          // 131,072
static constexpr size_t OFF_WIHG  = OFF_WHHL + 131072;          // 98,304
static constexpr size_t OFF_WHHG  = OFF_WIHG + 98304;           // 98,304
static constexpr size_t OFF_BIASL = OFF_WHHG + 98304;           // 2,048
static constexpr size_t OFF_FC1T  = OFF_BIASL + 2048;           // 81,920
static constexpr size_t OFF_FCOT  = OFF_FC1T + 81920;           // 40,960
static constexpr size_t OFF_HLAST = OFF_FCOT + 40960;           // 262,144

extern "C" void kernel_launch(void* const* d_in, const int* in_sizes, int n_in,
                              void* d_out, int out_size, void* d_ws, size_t ws_size,
                              hipStream_t stream) {
  (void)in_sizes; (void)n_in; (void)out_size; (void)ws_size;
  const float* x    = (const float*)d_in[0];
  const float* lWih = (const float*)d_in[1];
  const float* lWhh = (const float*)d_in[2];
  const float* lbih = (const float*)d_in[3];
  const float* lbhh = (const float*)d_in[4];
  const float* gWih = (const float*)d_in[5];
  const float* gWhh = (const float*)d_in[6];
  const float* gbih = (const float*)d_in[7];
  const float* gbhh = (const float*)d_in[8];
  const float* lnLg = (const float*)d_in[9];
  const float* lnLb = (const float*)d_in[10];
  const float* lnGg = (const float*)d_in[11];
  const float* lnGb = (const float*)d_in[12];
  const float* fc1W = (const float*)d_in[13];
  const float* fc1b = (const float*)d_in[14];
  const float* lnFg = (const float*)d_in[15];
  const float* lnFb = (const float*)d_in[16];
  const float* fcoW = (const float*)d_in[17];
  const float* fcob = (const float*)d_in[18];

  char* ws = (char*)d_ws;
  u16* xbf    = (u16*)(ws + OFF_XBF);
  u16* gx     = (u16*)(ws + OFF_GX);
  u16* lout   = (u16*)(ws + OFF_LOUT);
  u16* wihlb  = (u16*)(ws + OFF_WIHL);
  u16* whhlb  = (u16*)(ws + OFF_WHHL);
  u16* wihgb  = (u16*)(ws + OFF_WIHG);
  u16* whhgb  = (u16*)(ws + OFF_WHHG);
  float* biasl = (float*)(ws + OFF_BIASL);
  float* fc1Wt = (float*)(ws + OFF_FC1T);
  float* fcoWt = (float*)(ws + OFF_FCOT);
  float* hlast = (float*)(ws + OFF_HLAST);
  float* out   = (float*)d_out;

  prep_x<<<32768, 256, 0, stream>>>(x, xbf);
  prep_misc<<<1024, 256, 0, stream>>>(lWih, lWhh, gWih, gWhh, lbih, lbhh, fc1W, fcoW,
                                      wihlb, whhlb, wihgb, whhgb, biasl, fc1Wt, fcoWt);
  gemm_nt<<<dim3(2048, 4), 256, 0, stream>>>(xbf, wihlb, biasl, gx, 512);
  lstm_scan<<<32, 512, 0, stream>>>(gx, whhlb, lout);
  ln_pass<<<65536, 256, 0, stream>>>(lout, lnLg, lnLb);
  gemm_nt<<<dim3(2048, 3), 256, 0, stream>>>(lout, wihgb, gbih, gx, 384);
  gru_scan<<<32, 512, 0, stream>>>(gx, whhgb, gbhh, hlast);
  head<<<512, 256, 0, stream>>>(hlast, lnGg, lnGb, fc1Wt, fc1b, lnFg, lnFb, fcoWt, fcob, out);
}

// Round 4
// 1012.098 us; speedup vs baseline: 2.1784x; 1.3622x over previous
//
#include <hip/hip_runtime.h>

// ---------------------------------------------------------------------------
// LSTMGRUHybrid: B=512, T=512, D=128, H=128 (4H=512), G=128 (3G=384), F=160, C=64
// Round 4: scans are transcendental-issue-bound per CU. Spread batch over 4x
// more blocks (128 blk x 4 rows); batch rows placed at MFMA rows {0,4,8,12}
// so every lane owns exactly ONE gate element (reg 0) -> per-CU trans work /4.
// ---------------------------------------------------------------------------

typedef __attribute__((ext_vector_type(8))) short bf16x8;
typedef __attribute__((ext_vector_type(4))) float f32x4;
typedef __attribute__((ext_vector_type(4))) int i32x4;
typedef unsigned short u16;
typedef unsigned int u32;

#define BT 262144          // B*T
#define TT 512

__device__ __forceinline__ u16 f2bf(float f) {
  u32 u = __builtin_bit_cast(u32, f);
  u += 0x7fffu + ((u >> 16) & 1u);
  return (u16)(u >> 16);
}
__device__ __forceinline__ float bf2f(u16 h) {
  return __builtin_bit_cast(float, (u32)h << 16);
}
__device__ __forceinline__ u32 packbf2(float a, float b) {
  return (u32)f2bf(a) | ((u32)f2bf(b) << 16);
}
__device__ __forceinline__ bf16x8 ldg8(const u16* p) {
  return __builtin_bit_cast(bf16x8, *(const i32x4*)p);
}
__device__ __forceinline__ void g2lds16(const void* g, void* l) {
  __builtin_amdgcn_global_load_lds((const __attribute__((address_space(1))) void*)g,
                                   (__attribute__((address_space(3))) void*)l, 16, 0, 0);
}
// fast sigmoid/tanh: v_rcp instead of IEEE div sequence
__device__ __forceinline__ float frcp(float x) { return __builtin_amdgcn_rcpf(x); }
__device__ __forceinline__ float sigm(float x) { return frcp(1.f + __expf(-x)); }
__device__ __forceinline__ float tanh_f(float x) {
  return 1.f - 2.f * frcp(__expf(2.f * x) + 1.f);
}
// barrier that only drains LDS (not vmcnt) — keeps gx prefetch / lout stores
// off the per-step critical path. 0xC07F = vmcnt(63) expcnt(7) lgkmcnt(0).
__device__ __forceinline__ void scan_barrier() {
  __asm__ volatile("" ::: "memory");
  __builtin_amdgcn_s_waitcnt(0xC07F);
  __builtin_amdgcn_s_barrier();
  __asm__ volatile("" ::: "memory");
}

// ---------------------------------------------------------------------------
// prep kernels
// ---------------------------------------------------------------------------
__global__ void prep_x(const float* __restrict__ x, u16* __restrict__ xb) {
  size_t i = ((size_t)blockIdx.x * 256 + threadIdx.x) * 4;
  float4 v = *(const float4*)(x + i);
  *(uint2*)(xb + i) = make_uint2(packbf2(v.x, v.y), packbf2(v.z, v.w));
}

__global__ void prep_misc(
    const float* __restrict__ wihl, const float* __restrict__ whhl,
    const float* __restrict__ wihg, const float* __restrict__ whhg,
    const float* __restrict__ bihl, const float* __restrict__ bhhl,
    const float* __restrict__ fc1W, const float* __restrict__ fcoW,
    u16* __restrict__ wihlb, u16* __restrict__ whhlb,
    u16* __restrict__ wihgb, u16* __restrict__ whhgb,
    float* __restrict__ biasl, float* __restrict__ fc1Wt, float* __restrict__ fcoWt) {
  int i = blockIdx.x * 256 + threadIdx.x;
  if (i < 65536) {
    wihlb[i] = f2bf(wihl[i]);
  } else if (i < 131072) {
    int k = i - 65536; whhlb[k] = f2bf(whhl[k]);
  } else if (i < 180224) {
    int k = i - 131072; wihgb[k] = f2bf(wihg[k]);
  } else if (i < 229376) {
    int k = i - 180224; whhgb[k] = f2bf(whhg[k]);
  } else if (i < 229888) {
    int k = i - 229376; biasl[k] = bihl[k] + bhhl[k];
  } else if (i < 250368) {
    int k = i - 229888;                       // fc1Wt[g*160+f] = fc1W[f*128+g]
    fc1Wt[k] = fc1W[(k % 160) * 128 + (k / 160)];
  } else if (i < 260608) {
    int k = i - 250368;                       // fcoWt[f*64+c] = fcoW[c*160+f]
    fcoWt[k] = fcoW[(k % 64) * 160 + (k / 64)];
  }
}

// ---------------------------------------------------------------------------
// NT GEMM: C[M,N] bf16 = A[M,128] bf16 @ Bw[N,128]^T + bias[N]; tile 128x128
// ---------------------------------------------------------------------------
__global__ __launch_bounds__(256) void gemm_nt(
    const u16* __restrict__ A, const u16* __restrict__ Bw,
    const float* __restrict__ bias, u16* __restrict__ C, int N) {
  __shared__ __align__(16) u16 sA[128 * 128];
  __shared__ __align__(16) u16 sB[128 * 128];
  const int tid = threadIdx.x;
  const int w = tid >> 6, l = tid & 63;
  const size_t m0 = (size_t)blockIdx.x * 128;
  const int n0 = blockIdx.y * 128;
  const char* gA = (const char*)(A + m0 * 128);
  const char* gB = (const char*)(Bw + (size_t)n0 * 128);
  char* lA = (char*)sA;
  char* lB = (char*)sB;
#pragma unroll
  for (int i = 0; i < 8; i++) {
    int ubase = (w * 8 + i) << 10;   // 1KB per wave-inst
    int off = ubase + (l << 4);
    g2lds16(gA + off, lA + ubase);
    g2lds16(gB + off, lB + ubase);
  }
  __syncthreads();
  const int mq = (w >> 1) * 64, nq = (w & 1) * 64;
  f32x4 acc[4][4];
#pragma unroll
  for (int i = 0; i < 4; i++)
#pragma unroll
    for (int j = 0; j < 4; j++) acc[i][j] = (f32x4){0.f, 0.f, 0.f, 0.f};
#pragma unroll
  for (int k0 = 0; k0 < 4; k0++) {
    const int koff = k0 * 32 + (l >> 4) * 8;
    bf16x8 af[4], bf[4];
#pragma unroll
    for (int i = 0; i < 4; i++) af[i] = ldg8(&sA[(mq + i * 16 + (l & 15)) * 128 + koff]);
#pragma unroll
    for (int j = 0; j < 4; j++) bf[j] = ldg8(&sB[(nq + j * 16 + (l & 15)) * 128 + koff]);
#pragma unroll
    for (int i = 0; i < 4; i++)
#pragma unroll
      for (int j = 0; j < 4; j++)
        acc[i][j] = __builtin_amdgcn_mfma_f32_16x16x32_bf16(af[i], bf[j], acc[i][j], 0, 0, 0);
  }
  float bv[4];
#pragma unroll
  for (int j = 0; j < 4; j++) bv[j] = bias[n0 + nq + j * 16 + (l & 15)];
  __syncthreads();
  u16* sOut = sA;  // reuse
#pragma unroll
  for (int i = 0; i < 4; i++)
#pragma unroll
    for (int j = 0; j < 4; j++)
#pragma unroll
      for (int r = 0; r < 4; r++)
        sOut[(mq + i * 16 + (l >> 4) * 4 + r) * 128 + nq + j * 16 + (l & 15)] =
            f2bf(acc[i][j][r] + bv[j]);
  __syncthreads();
#pragma unroll
  for (int p = 0; p < 8; p++) {
    int e = (p * 256 + tid) * 8;  // element index within 128x128 tile
    int row = e >> 7, col = e & 127;
    *(i32x4*)(C + (m0 + row) * (size_t)N + n0 + col) = *(const i32x4*)&sOut[e];
  }
}

// ---------------------------------------------------------------------------
// LSTM scan. 128 blocks x 512 thr; 4 batch rows/block at MFMA rows {0,4,8,12}
// so each lane owns exactly one gate element (C reg 0). Wave w owns hidden
// cols [w*16, w*16+16); its 4 MFMA N-tiles are the 4 gates at that col slice.
// ---------------------------------------------------------------------------
__global__ __launch_bounds__(512) void lstm_scan(
    const u16* __restrict__ gx,   // [BT][512] bf16 (x-proj + bih + bhh)
    const u16* __restrict__ whh,  // [512][128] bf16
    u16* __restrict__ lout) {     // [B][T][128] bf16, RAW h (LN applied later)
  const int tid = threadIdx.x;
  const int w = tid >> 6, l = tid & 63;
  const int hc = l & 15, q = l >> 4;
  const int col = w * 16 + hc;
  const int b0 = blockIdx.x * 4;        // 4 batch rows per block
  const int mrow = q * 4;               // MFMA row owned by this lane (reg 0)
  __shared__ __align__(16) u16 hb0[16 * 136];
  __shared__ __align__(16) u16 hb1[16 * 136];

  bf16x8 wf[4][4];
#pragma unroll
  for (int g = 0; g < 4; g++)
#pragma unroll
    for (int k0 = 0; k0 < 4; k0++)
      wf[g][k0] = ldg8(&whh[(g * 128 + col) * 128 + k0 * 32 + q * 8]);

  float c = 0.f;
  u32 goff = (u32)(b0 + q) * (TT * 512) + col;
  u32 loff = (u32)(b0 + q) * (TT * 128) + col;
  for (int i = tid; i < 16 * 136; i += 512) { hb0[i] = 0; hb1[i] = 0; }

  u16 ga[4], gb[4];
#pragma unroll
  for (int g = 0; g < 4; g++) ga[g] = gx[goff + g * 128];
  goff += 512;
  scan_barrier();

  auto step = [&](u16 (&gc)[4], u16 (&gp)[4], const u16* hrd, u16* hwr) {
    // prefetch t+1 (vmcnt NOT drained at barrier; lands by next gate phase)
#pragma unroll
    for (int g = 0; g < 4; g++) gp[g] = gx[goff + g * 128];
    goff += 512;
    // h_prev @ Whh^T  (A rows {0,4,8,12} hold the 4 batch rows; rest zero)
    bf16x8 af[4];
#pragma unroll
    for (int k0 = 0; k0 < 4; k0++)
      af[k0] = ldg8(&hrd[hc * 136 + k0 * 32 + q * 8]);
    f32x4 acc[4];
#pragma unroll
    for (int g = 0; g < 4; g++) acc[g] = (f32x4){0.f, 0.f, 0.f, 0.f};
#pragma unroll
    for (int k0 = 0; k0 < 4; k0++)
#pragma unroll
      for (int g = 0; g < 4; g++)
        acc[g] = __builtin_amdgcn_mfma_f32_16x16x32_bf16(af[k0], wf[g][k0], acc[g], 0, 0, 0);
    // single gate element per lane (reg 0 == MFMA row q*4 == batch b0+q)
    float pi = acc[0][0] + bf2f(gc[0]);
    float pf = acc[1][0] + bf2f(gc[1]);
    float pg = acc[2][0] + bf2f(gc[2]);
    float po = acc[3][0] + bf2f(gc[3]);
    c = sigm(pf) * c + sigm(pi) * tanh_f(pg);
    float h = sigm(po) * tanh_f(c);
    u16 hv = f2bf(h);
    hwr[mrow * 136 + col] = hv;
    lout[loff] = hv;
    loff += 128;
    scan_barrier();
  };

#pragma unroll 1
  for (int t2 = 0; t2 < TT; t2 += 2) {
    step(ga, gb, hb0, hb1);
    step(gb, ga, hb1, hb0);
  }
}

// ---------------------------------------------------------------------------
// In-place row LayerNorm over [BT][128] bf16. One wave per row.
// ---------------------------------------------------------------------------
__global__ __launch_bounds__(256) void ln_pass(
    u16* __restrict__ buf, const float* __restrict__ g, const float* __restrict__ b) {
  const size_t row = (size_t)blockIdx.x * 4 + (threadIdx.x >> 6);
  const int l = threadIdx.x & 63;
  u16* p = buf + row * 128 + l * 2;
  u32 v = *(const u32*)p;
  float a0 = bf2f((u16)v), a1 = bf2f((u16)(v >> 16));
  float s1 = a0 + a1, s2 = a0 * a0 + a1 * a1;
#pragma unroll
  for (int m = 1; m < 64; m <<= 1) { s1 += __shfl_xor(s1, m); s2 += __shfl_xor(s2, m); }
  float mean = s1 * 0.0078125f;
  float var = s2 * 0.0078125f - mean * mean;
  float rs = rsqrtf(var + 1e-5f);
  float2 gg = *(const float2*)(g + l * 2);
  float2 bb = *(const float2*)(b + l * 2);
  float y0 = (a0 - mean) * rs * gg.x + bb.x;
  float y1 = (a1 - mean) * rs * gg.y + bb.y;
  *(u32*)p = packbf2(y0, y1);
}

// ---------------------------------------------------------------------------
// GRU scan -> final hidden only. 128 blocks x 4 rows, same row-spreading.
// ---------------------------------------------------------------------------
__global__ __launch_bounds__(512) void gru_scan(
    const u16* __restrict__ gx,   // [BT][384] bf16 (x-proj + bih)
    const u16* __restrict__ whh,  // [384][128] bf16
    const float* __restrict__ bhh,
    float* __restrict__ hlast) {  // [512][128] fp32
  const int tid = threadIdx.x;
  const int w = tid >> 6, l = tid & 63;
  const int hc = l & 15, q = l >> 4;
  const int col = w * 16 + hc;
  const int b0 = blockIdx.x * 4;
  const int mrow = q * 4;
  __shared__ __align__(16) u16 hb0[16 * 136];
  __shared__ __align__(16) u16 hb1[16 * 136];

  bf16x8 wf[3][4];
#pragma unroll
  for (int g = 0; g < 3; g++)
#pragma unroll
    for (int k0 = 0; k0 < 4; k0++)
      wf[g][k0] = ldg8(&whh[(g * 128 + col) * 128 + k0 * 32 + q * 8]);

  const float bhr = bhh[col], bhz = bhh[128 + col], bhn = bhh[256 + col];
  float hp = 0.f;
  u32 goff = (u32)(b0 + q) * (TT * 384) + col;
  for (int i = tid; i < 16 * 136; i += 512) { hb0[i] = 0; hb1[i] = 0; }

  u16 ga[3], gb[3];
#pragma unroll
  for (int g = 0; g < 3; g++) ga[g] = gx[goff + g * 128];
  goff += 384;
  scan_barrier();

  auto step = [&](u16 (&gc)[3], u16 (&gp)[3], const u16* hrd, u16* hwr) {
#pragma unroll
    for (int g = 0; g < 3; g++) gp[g] = gx[goff + g * 128];
    goff += 384;
    bf16x8 af[4];
#pragma unroll
    for (int k0 = 0; k0 < 4; k0++)
      af[k0] = ldg8(&hrd[hc * 136 + k0 * 32 + q * 8]);
    f32x4 acc[3];
#pragma unroll
    for (int g = 0; g < 3; g++) acc[g] = (f32x4){0.f, 0.f, 0.f, 0.f};
#pragma unroll
    for (int k0 = 0; k0 < 4; k0++)
#pragma unroll
      for (int g = 0; g < 3; g++)
        acc[g] = __builtin_amdgcn_mfma_f32_16x16x32_bf16(af[k0], wf[g][k0], acc[g], 0, 0, 0);
    float rr = sigm(bf2f(gc[0]) + acc[0][0] + bhr);
    float zz = sigm(bf2f(gc[1]) + acc[1][0] + bhz);
    float nn = tanh_f(bf2f(gc[2]) + rr * (acc[2][0] + bhn));
    hp = nn + zz * (hp - nn);
    hwr[mrow * 136 + col] = f2bf(hp);
    scan_barrier();
  };

#pragma unroll 1
  for (int t2 = 0; t2 < TT; t2 += 2) {
    step(ga, gb, hb0, hb1);
    step(gb, ga, hb1, hb0);
  }
  hlast[(size_t)(b0 + q) * 128 + col] = hp;
}

// ---------------------------------------------------------------------------
// Head: LN(gru) -> relu -> fc1 -> LN(fc1) -> relu -> fco. One block per row.
// ---------------------------------------------------------------------------
__global__ __launch_bounds__(256) void head(
    const float* __restrict__ hlast,
    const float* __restrict__ g1, const float* __restrict__ b1,
    const float* __restrict__ fc1Wt, const float* __restrict__ fc1b,
    const float* __restrict__ g2, const float* __restrict__ b2,
    const float* __restrict__ fcoWt, const float* __restrict__ fcob,
    float* __restrict__ out) {
  const int b = blockIdx.x, tid = threadIdx.x;
  __shared__ float yv[128];
  __shared__ float zv[160];
  __shared__ float red[8];
  float v = (tid < 128) ? hlast[b * 128 + tid] : 0.f;
  float p1 = v, p2 = v * v;
#pragma unroll
  for (int m = 1; m < 64; m <<= 1) { p1 += __shfl_xor(p1, m); p2 += __shfl_xor(p2, m); }
  if ((tid & 63) == 0) { red[(tid >> 6) * 2] = p1; red[(tid >> 6) * 2 + 1] = p2; }
  __syncthreads();
  float s1 = red[0] + red[2] + red[4] + red[6];
  float s2 = red[1] + red[3] + red[5] + red[7];
  float mean = s1 * (1.f / 128.f);
  float var = s2 * (1.f / 128.f) - mean * mean;
  float rs = rsqrtf(var + 1e-5f);
  if (tid < 128) yv[tid] = fmaxf((v - mean) * rs * g1[tid] + b1[tid], 0.f);
  __syncthreads();
  float z = 0.f;
  if (tid < 160) {
    z = fc1b[tid];
    for (int g = 0; g < 128; g++) z += yv[g] * fc1Wt[g * 160 + tid];
  }
  float q1 = (tid < 160) ? z : 0.f;
  float q2 = (tid < 160) ? z * z : 0.f;
#pragma unroll
  for (int m = 1; m < 64; m <<= 1) { q1 += __shfl_xor(q1, m); q2 += __shfl_xor(q2, m); }
  __syncthreads();
  if ((tid & 63) == 0) { red[(tid >> 6) * 2] = q1; red[(tid >> 6) * 2 + 1] = q2; }
  __syncthreads();
  s1 = red[0] + red[2] + red[4] + red[6];
  s2 = red[1] + red[3] + red[5] + red[7];
  mean = s1 * (1.f / 160.f);
  var = s2 * (1.f / 160.f) - mean * mean;
  rs = rsqrtf(var + 1e-5f);
  if (tid < 160) zv[tid] = fmaxf((z - mean) * rs * g2[tid] + b2[tid], 0.f);
  __syncthreads();
  if (tid < 64) {
    float o = fcob[tid];
    for (int f = 0; f < 160; f++) o += zv[f] * fcoWt[f * 64 + tid];
    out[b * 64 + tid] = o;
  }
}

// ---------------------------------------------------------------------------
// workspace layout (bytes) — total ~404 MB; gx region shared by LSTM/GRU phases
// ---------------------------------------------------------------------------
static constexpr size_t OFF_XBF   = 0;                          // 67,108,864
static constexpr size_t OFF_GX    = 67108864;                   // 268,435,456
static constexpr size_t OFF_LOUT  = OFF_GX + 268435456;         // 67,108,864
static constexpr size_t OFF_WIHL  = OFF_LOUT + 67108864;        // 131,072
static constexpr size_t OFF_WHHL  = OFF_WIHL + 131072;          // 131,072
static constexpr size_t OFF_WIHG  = OFF_WHHL + 131072;          // 98,304
static constexpr size_t OFF_WHHG  = OFF_WIHG + 98304;           // 98,304
static constexpr size_t OFF_BIASL = OFF_WHHG + 98304;           // 2,048
static constexpr size_t OFF_FC1T  = OFF_BIASL + 2048;           // 81,920
static constexpr size_t OFF_FCOT  = OFF_FC1T + 81920;           // 40,960
static constexpr size_t OFF_HLAST = OFF_FCOT + 40960;           // 262,144

extern "C" void kernel_launch(void* const* d_in, const int* in_sizes, int n_in,
                              void* d_out, int out_size, void* d_ws, size_t ws_size,
                              hipStream_t stream) {
  (void)in_sizes; (void)n_in; (void)out_size; (void)ws_size;
  const float* x    = (const float*)d_in[0];
  const float* lWih = (const float*)d_in[1];
  const float* lWhh = (const float*)d_in[2];
  const float* lbih = (const float*)d_in[3];
  const float* lbhh = (const float*)d_in[4];
  const float* gWih = (const float*)d_in[5];
  const float* gWhh = (const float*)d_in[6];
  const float* gbih = (const float*)d_in[7];
  const float* gbhh = (const float*)d_in[8];
  const float* lnLg = (const float*)d_in[9];
  const float* lnLb = (const float*)d_in[10];
  const float* lnGg = (const float*)d_in[11];
  const float* lnGb = (const float*)d_in[12];
  const float* fc1W = (const float*)d_in[13];
  const float* fc1b = (const float*)d_in[14];
  const float* lnFg = (const float*)d_in[15];
  const float* lnFb = (const float*)d_in[16];
  const float* fcoW = (const float*)d_in[17];
  const float* fcob = (const float*)d_in[18];

  char* ws = (char*)d_ws;
  u16* xbf    = (u16*)(ws + OFF_XBF);
  u16* gx     = (u16*)(ws + OFF_GX);
  u16* lout   = (u16*)(ws + OFF_LOUT);
  u16* wihlb  = (u16*)(ws + OFF_WIHL);
  u16* whhlb  = (u16*)(ws + OFF_WHHL);
  u16* wihgb  = (u16*)(ws + OFF_WIHG);
  u16* whhgb  = (u16*)(ws + OFF_WHHG);
  float* biasl = (float*)(ws + OFF_BIASL);
  float* fc1Wt = (float*)(ws + OFF_FC1T);
  float* fcoWt = (float*)(ws + OFF_FCOT);
  float* hlast = (float*)(ws + OFF_HLAST);
  float* out   = (float*)d_out;

  prep_x<<<32768, 256, 0, stream>>>(x, xbf);
  prep_misc<<<1024, 256, 0, stream>>>(lWih, lWhh, gWih, gWhh, lbih, lbhh, fc1W, fcoW,
                                      wihlb, whhlb, wihgb, whhgb, biasl, fc1Wt, fcoWt);
  gemm_nt<<<dim3(2048, 4), 256, 0, stream>>>(xbf, wihlb, biasl, gx, 512);
  lstm_scan<<<128, 512, 0, stream>>>(gx, whhlb, lout);
  ln_pass<<<65536, 256, 0, stream>>>(lout, lnLg, lnLb);
  gemm_nt<<<dim3(2048, 3), 256, 0, stream>>>(lout, wihgb, gbih, gx, 384);
  gru_scan<<<128, 512, 0, stream>>>(gx, whhgb, gbhh, hlast);
  head<<<512, 256, 0, stream>>>(hlast, lnGg, lnGb, fc1Wt, fc1b, lnFg, lnFb, fcoWt, fcob, out);
}